// Round 9
// baseline (658.474 us; speedup 1.0000x reference)
//
// CausalDecayMemory v9: ONE cooperative mega-kernel (512 blocks x 256 thr =
// exactly 2 blocks/CU co-resident) with grid.sync() between phases.
// Why: accounting across v3-v8 shows ~19us inter-kernel launch gap; at 5
// launches that's ~84us of the 176.8us wall -- larger than any kernel.
// Phases are the byte-identical v7 bodies (v8's fp32-fused qkv REVERTED:
// FETCH 22.6->55MB, VALU 2x, compiler sank the staging loads):
//  P0 convert (grid-stride) | P1 qkv 3 tiles/block (id=bid+512r keeps XCD
//  affinity) | P2 score (384/512 blocks) | P3 pv | P4 out.
// Buffer lifetimes (xbf dead after P1, P overlays xbf, P dead before out,
// retr overwrites qb after P2 reads it) now enforced by grid.sync.
// Fallback: if cooperative launch errors, run the 5-kernel v7 path.
#include <hip/hip_runtime.h>
#include <hip/hip_cooperative_groups.h>
namespace cg = cooperative_groups;

#define T_SEQ 4096

typedef __attribute__((ext_vector_type(8))) short short8;
typedef __attribute__((ext_vector_type(4))) float float4v;
typedef __attribute__((ext_vector_type(4))) unsigned short us4;

__device__ __forceinline__ unsigned short f2bf(float f) {
  union { float f; unsigned u; } x; x.f = f;
  return (unsigned short)((x.u + 0x7FFFu + ((x.u >> 16) & 1u)) >> 16);
}

__device__ __forceinline__ float4v mfma16(short8 a, short8 b, float4v c) {
  return __builtin_amdgcn_mfma_f32_16x16x32_bf16(a, b, c, 0, 0, 0);
}

#define GLD16(g, l)                                                          \
  __builtin_amdgcn_global_load_lds(                                          \
      (const __attribute__((address_space(1))) void*)(g),                    \
      (__attribute__((address_space(3))) void*)(l), 16, 0, 0)

// ---- shared staging macros (reference enclosing-scope locals) ----
#define STAGE_QKV(bi, k0)                                                    \
  {                                                                          \
    _Pragma("unroll") for (int i = 0; i < 4; ++i) {                          \
      const int s = i * 256 + tid;                                           \
      const int row = s >> 3;                                                \
      const int kc = (s & 7) ^ (row & 7);                                    \
      GLD16(A + (size_t)(m0 + row) * 512 + (k0) + kc * 8,                    \
            &As[bi][(i * 256 + wave * 64) * 8]);                             \
    }                                                                        \
    _Pragma("unroll") for (int i = 0; i < 4; ++i) {                          \
      const int s = i * 256 + tid;                                           \
      const int row = s >> 3;                                                \
      const int kc = (s & 7) ^ (row & 7);                                    \
      GLD16(Bw + (size_t)(nb0 + row) * 512 + (k0) + kc * 8,                  \
            &Bs[bi][(i * 256 + wave * 64) * 8]);                             \
    }                                                                        \
  }

#define STAGE_SC(bi, k0)                                                     \
  {                                                                          \
    _Pragma("unroll") for (int i = 0; i < 4; ++i) {                          \
      const int s = i * 256 + tid;                                           \
      const int row = s >> 3;                                                \
      const int kc = (s & 7) ^ (row & 7);                                    \
      GLD16(qb + (size_t)(m0 + row) * 512 + (k0) + kc * 8,                   \
            &As[bi][(i * 256 + wave * 64) * 8]);                             \
    }                                                                        \
    _Pragma("unroll") for (int i = 0; i < 4; ++i) {                          \
      const int s = i * 256 + tid;                                           \
      const int row = s >> 3;                                                \
      const int kc = (s & 7) ^ (row & 7);                                    \
      int sl = s0 + row;                                                     \
      if (sl > T_SEQ - 1) sl = T_SEQ - 1;                                    \
      GLD16(kb + ((size_t)(b * T_SEQ + sl)) * 512 + (k0) + kc * 8,           \
            &Bs[bi][(i * 256 + wave * 64) * 8]);                             \
    }                                                                        \
  }

#define STAGE_PV(bi, k0)                                                     \
  {                                                                          \
    _Pragma("unroll") for (int i = 0; i < 4; ++i) {                          \
      const int s = i * 256 + tid;                                           \
      const int row = s >> 3;                                                \
      const int kc = (s & 7) ^ (row & 7);                                    \
      GLD16(P + (size_t)(m0 + row) * 384 + (k0) + kc * 8,                    \
            &As[bi][(i * 256 + wave * 64) * 8]);                             \
    }                                                                        \
    _Pragma("unroll") for (int i = 0; i < 4; ++i) {                          \
      const int s = i * 256 + tid;                                           \
      const int row = s >> 3;                                                \
      const int kc = (s & 7) ^ (row & 7);                                    \
      int tt = t0 + (k0) + kc * 8;                                           \
      if (tt > T_SEQ - 8) tt = T_SEQ - 8;                                    \
      GLD16(vT + (((size_t)(b * 512 + n0 + row)) << 12) + tt,                \
            &Bs[bi][(i * 256 + wave * 64) * 8]);                             \
    }                                                                        \
  }

#define STAGE_OUT(bi, k0)                                                    \
  {                                                                          \
    _Pragma("unroll") for (int i = 0; i < 4; ++i) {                          \
      const int s = i * 256 + tid;                                           \
      const int row = s >> 3;                                                \
      const int kc = (s & 7) ^ (row & 7);                                    \
      GLD16(A + (size_t)(m0 + row) * 512 + (k0) + kc * 8,                    \
            &As[bi][(i * 256 + wave * 64) * 8]);                             \
    }                                                                        \
    _Pragma("unroll") for (int i = 0; i < 4; ++i) {                          \
      const int s = i * 256 + tid;                                           \
      const int row = s >> 3;                                                \
      const int kc = (s & 7) ^ (row & 7);                                    \
      const float* gw = Wo + (size_t)(n0 + row) * 512 + (k0) + kc * 8;       \
      const float4v w0 = ((const float4v*)gw)[0];                            \
      const float4v w1 = ((const float4v*)gw)[1];                            \
      short8 pk;                                                             \
      _Pragma("unroll") for (int r = 0; r < 4; ++r) {                        \
        pk[r] = (short)f2bf(w0[r]);                                          \
        pk[4 + r] = (short)f2bf(w1[r]);                                      \
      }                                                                      \
      *(short8*)&Bs[bi][s * 8] = pk;                                         \
    }                                                                        \
  }

// 16 MFMA inner step shared by all GEMM phases
#define GEMM_STEP(bi)                                                        \
  _Pragma("unroll") for (int ks = 0; ks < 2; ++ks) {                         \
    const int off = ((ks * 4 + quad) ^ xr) * 8;                              \
    short8 af[4], bf[4];                                                     \
    _Pragma("unroll") for (int mt = 0; mt < 4; ++mt)                         \
      af[mt] = *(const short8*)&As[bi][(wm * 64 + mt * 16 + l16) * 64 + off];\
    _Pragma("unroll") for (int nt = 0; nt < 4; ++nt)                         \
      bf[nt] = *(const short8*)&Bs[bi][(wn * 64 + nt * 16 + l16) * 64 + off];\
    _Pragma("unroll") for (int nt = 0; nt < 4; ++nt)                         \
      _Pragma("unroll") for (int mt = 0; mt < 4; ++mt)                       \
        acc[mt][nt] = mfma16(af[mt], bf[nt], acc[mt][nt]);                   \
  }

// ===========================================================================
// Cooperative mega-kernel: all 5 phases, grid.sync between.
// ===========================================================================
__global__ __launch_bounds__(256, 2) void mega(
    const float4v* __restrict__ Xf, const float4v* __restrict__ Wqf,
    const float4v* __restrict__ Wkf, const float4v* __restrict__ Wvf,
    const float* __restrict__ Wo, const float* __restrict__ dlp,
    const float* __restrict__ oscp, unsigned short* __restrict__ qb,
    unsigned short* __restrict__ kb, unsigned short* __restrict__ vT,
    unsigned short* __restrict__ xbf, unsigned short* __restrict__ wcat,
    unsigned short* __restrict__ P, float* __restrict__ out) {
  __shared__ unsigned short As[2][8192];
  __shared__ unsigned short Bs[2][8192];
  cg::grid_group gg = cg::this_grid();
  const int tid = threadIdx.x;
  const int wave = tid >> 6, lane = tid & 63, quad = lane >> 4, l16 = lane & 15;
  const int wm = wave >> 1, wn = wave & 1;
  const int xr = l16 & 7;
  const int bid = blockIdx.x;

  // ---- P0: fp32 -> bf16 convert (grid-stride) ----
  {
    us4* xbf4 = (us4*)xbf;
    us4* wcat4 = (us4*)wcat;
    const int XG = 2097152, WG = 65536, TOT = XG + 3 * WG;
    for (int g = bid * 256 + tid; g < TOT; g += 512 * 256) {
      float4v v;
      us4* dst;
      if (g < XG) {
        v = Xf[g];
        dst = xbf4 + g;
      } else {
        const int g2 = g - XG;
        const float4v* W = (g2 < WG) ? Wqf : (g2 < 2 * WG) ? Wkf : Wvf;
        v = W[g2 & (WG - 1)];
        dst = wcat4 + g2;
      }
      us4 p;
#pragma unroll
      for (int r = 0; r < 4; ++r) p[r] = f2bf(v[r]);
      *dst = p;
    }
  }
  __threadfence();
  gg.sync();

  // ---- P1: QKV GEMM, 3 tiles/block (id = bid + 512*rr keeps XCD id&7) ----
  for (int rr = 0; rr < 3; ++rr) {
    const int id = bid + 512 * rr;
    const int r8 = id & 7, j = id >> 3;
    const int m0 = (r8 * 16 + j / 12) * 128;
    const int by = j % 12;
    const int wid = by >> 2;
    const int n0 = (by & 3) * 128;
    const int nb0 = wid * 512 + n0;
    const unsigned short* A = xbf;
    const unsigned short* Bw = wcat;

    float4v acc[4][4];
#pragma unroll
    for (int i = 0; i < 4; ++i)
#pragma unroll
      for (int jj = 0; jj < 4; ++jj) acc[i][jj] = (float4v)0.f;

    STAGE_QKV(0, 0);
    __syncthreads();
    for (int t = 0; t < 8; ++t) {
      const int bi = t & 1;
      if (t < 7) STAGE_QKV(bi ^ 1, (t + 1) * 64);
      GEMM_STEP(bi);
      __syncthreads();
    }

    const int row0 = m0 + wm * 64;
    if (wid < 2) {
      unsigned short* outp = (wid == 0) ? qb : kb;
#pragma unroll
      for (int mt = 0; mt < 4; ++mt) {
        const int row = row0 + mt * 16 + quad * 4;
#pragma unroll
        for (int nt = 0; nt < 4; ++nt) {
          const int col = n0 + wn * 64 + nt * 16 + l16;
#pragma unroll
          for (int r = 0; r < 4; ++r)
            outp[(size_t)(row + r) * 512 + col] = f2bf(acc[mt][nt][r]);
        }
      }
    } else {
#pragma unroll
      for (int mt = 0; mt < 4; ++mt) {
        const int row = row0 + mt * 16 + quad * 4;
        const int b = row >> 12, t = row & (T_SEQ - 1);
#pragma unroll
        for (int nt = 0; nt < 4; ++nt) {
          const int d = n0 + wn * 64 + nt * 16 + l16;
          us4 pk;
#pragma unroll
          for (int r = 0; r < 4; ++r) pk[r] = f2bf(acc[mt][nt][r]);
          *(us4*)&vT[(((size_t)(b * 512 + d)) << 12) + t] = pk;
        }
      }
    }
  }
  __threadfence();
  gg.sync();

  // ---- P2: attn_score (384 of 512 blocks) ----
  if (bid < 384) {
    const int id = bid;
    const int r8 = id & 7, j = id >> 3;  // j 0..47
    const int mt0 = r8 * 16 + j / 3;     // m-tile 0..127
    const int sub = j % 3;
    const int m0 = mt0 * 128;
    const int b = mt0 >> 5;
    const int t0 = (mt0 & 31) * 128;
    const int s0 = t0 + sub * 128;

    const float dl = dlp[0];
    const float decay = 1.f / (1.f + __expf(-dl));
    const float l2d = __log2f(decay);

    float4v acc[4][4];
#pragma unroll
    for (int i = 0; i < 4; ++i)
#pragma unroll
      for (int jj = 0; jj < 4; ++jj) acc[i][jj] = (float4v)0.f;

    STAGE_SC(0, 0);
    __syncthreads();
    for (int t = 0; t < 8; ++t) {
      const int bi = t & 1;
      if (t < 7) STAGE_SC(bi ^ 1, (t + 1) * 64);
      GEMM_STEP(bi);
      __syncthreads();
    }

#pragma unroll
    for (int mtq = 0; mtq < 4; ++mtq) {
      const int mloc = wm * 64 + mtq * 16 + quad * 4;
#pragma unroll
      for (int nt = 0; nt < 4; ++nt) {
        const int scol = sub * 128 + wn * 64 + nt * 16 + l16;
        const int valid_s = (t0 + scol < T_SEQ) ? 1 : 0;
#pragma unroll
        for (int r = 0; r < 4; ++r) {
          const int dd = scol - (mloc + r);
          float w = 0.f;
          if (dd > 0 && valid_s) w = exp2f((float)(dd - 1) * l2d);
          P[(size_t)(m0 + mloc + r) * 384 + scol] = f2bf(acc[mtq][nt][r] * w);
        }
      }
    }
  }
  __threadfence();
  gg.sync();

  // ---- P3: attn_pv (retr overlays qb) ----
  {
    const int id = bid;
    const int r8 = id & 7, j = id >> 3;  // j 0..63
    const int mt0 = r8 * 16 + j / 4;
    const int n0 = (j % 4) * 128;
    const int m0 = mt0 * 128;
    const int b = mt0 >> 5;
    const int t0 = (mt0 & 31) * 128;
    unsigned short* retr = qb;

    float4v acc[4][4];
#pragma unroll
    for (int i = 0; i < 4; ++i)
#pragma unroll
      for (int jj = 0; jj < 4; ++jj) acc[i][jj] = (float4v)0.f;

    STAGE_PV(0, 0);
    __syncthreads();
    for (int t = 0; t < 6; ++t) {
      const int bi = t & 1;
      if (t < 5) STAGE_PV(bi ^ 1, (t + 1) * 64);
      GEMM_STEP(bi);
      __syncthreads();
    }

    const int row0 = m0 + wm * 64;
#pragma unroll
    for (int mtq = 0; mtq < 4; ++mtq) {
      const int row = row0 + mtq * 16 + quad * 4;
#pragma unroll
      for (int nt = 0; nt < 4; ++nt) {
        const int col = n0 + wn * 64 + nt * 16 + l16;
#pragma unroll
        for (int r = 0; r < 4; ++r)
          retr[(size_t)(row + r) * 512 + col] = f2bf(acc[mtq][nt][r]);
      }
    }
  }
  __threadfence();
  gg.sync();

  // ---- P4: out projection ----
  {
    const int id = bid;
    const int r8 = id & 7, j = id >> 3;
    const int m0 = (r8 * 16 + j / 4) * 128;
    const int n0 = (j % 4) * 128;
    const float scale = oscp[0];
    const unsigned short* A = qb;

    float4v acc[4][4];
#pragma unroll
    for (int i = 0; i < 4; ++i)
#pragma unroll
      for (int jj = 0; jj < 4; ++jj) acc[i][jj] = (float4v)0.f;

    STAGE_OUT(0, 0);
    __syncthreads();
    for (int t = 0; t < 8; ++t) {
      const int bi = t & 1;
      if (t < 7) STAGE_OUT(bi ^ 1, (t + 1) * 64);
      GEMM_STEP(bi);
      __syncthreads();
    }

    const int row0 = m0 + wm * 64;
#pragma unroll
    for (int mt = 0; mt < 4; ++mt) {
      const int row = row0 + mt * 16 + quad * 4;
#pragma unroll
      for (int nt = 0; nt < 4; ++nt) {
        const int col = n0 + wn * 64 + nt * 16 + l16;
#pragma unroll
        for (int r = 0; r < 4; ++r)
          out[(size_t)(row + r) * 512 + col] = acc[mt][nt][r] * scale;
      }
    }
  }
}

// ===========================================================================
// Fallback path: the 5 separate v7 kernels (used if cooperative launch fails)
// ===========================================================================
__global__ __launch_bounds__(256) void convert_pre(
    const float4v* __restrict__ X, const float4v* __restrict__ Wq,
    const float4v* __restrict__ Wk, const float4v* __restrict__ Wv,
    us4* __restrict__ xbf, us4* __restrict__ wcat) {
  const int gid = blockIdx.x * 256 + threadIdx.x;
  const int XG = 2097152, WG = 65536;
  float4v v;
  us4* dst;
  if (gid < XG) {
    v = X[gid];
    dst = xbf + gid;
  } else {
    const int g2 = gid - XG;
    const float4v* W = (g2 < WG) ? Wq : (g2 < 2 * WG) ? Wk : Wv;
    v = W[g2 & (WG - 1)];
    dst = wcat + g2;
  }
  us4 p;
#pragma unroll
  for (int r = 0; r < 4; ++r) p[r] = f2bf(v[r]);
  *dst = p;
}

__global__ __launch_bounds__(256, 2) void gemm_qkv(
    const unsigned short* __restrict__ A, const unsigned short* __restrict__ Bw,
    unsigned short* __restrict__ qb, unsigned short* __restrict__ kb,
    unsigned short* __restrict__ vT) {
  __shared__ unsigned short As[2][8192];
  __shared__ unsigned short Bs[2][8192];
  const int tid = threadIdx.x;
  const int wave = tid >> 6, lane = tid & 63, quad = lane >> 4, l16 = lane & 15;
  const int wm = wave >> 1, wn = wave & 1;
  const int id = blockIdx.x;
  const int r8 = id & 7, j = id >> 3;
  const int m0 = (r8 * 16 + j / 12) * 128;
  const int by = j % 12;
  const int wid = by >> 2;
  const int n0 = (by & 3) * 128;
  const int nb0 = wid * 512 + n0;
  const int xr = l16 & 7;

  float4v acc[4][4];
#pragma unroll
  for (int i = 0; i < 4; ++i)
#pragma unroll
    for (int jj = 0; jj < 4; ++jj) acc[i][jj] = (float4v)0.f;

  STAGE_QKV(0, 0);
  __syncthreads();
  for (int t = 0; t < 8; ++t) {
    const int bi = t & 1;
    if (t < 7) STAGE_QKV(bi ^ 1, (t + 1) * 64);
    GEMM_STEP(bi);
    __syncthreads();
  }

  const int row0 = m0 + wm * 64;
  if (wid < 2) {
    unsigned short* outp = (wid == 0) ? qb : kb;
#pragma unroll
    for (int mt = 0; mt < 4; ++mt) {
      const int row = row0 + mt * 16 + quad * 4;
#pragma unroll
      for (int nt = 0; nt < 4; ++nt) {
        const int col = n0 + wn * 64 + nt * 16 + l16;
#pragma unroll
        for (int r = 0; r < 4; ++r)
          outp[(size_t)(row + r) * 512 + col] = f2bf(acc[mt][nt][r]);
      }
    }
  } else {
#pragma unroll
    for (int mt = 0; mt < 4; ++mt) {
      const int row = row0 + mt * 16 + quad * 4;
      const int b = row >> 12, t = row & (T_SEQ - 1);
#pragma unroll
      for (int nt = 0; nt < 4; ++nt) {
        const int d = n0 + wn * 64 + nt * 16 + l16;
        us4 pk;
#pragma unroll
        for (int r = 0; r < 4; ++r) pk[r] = f2bf(acc[mt][nt][r]);
        *(us4*)&vT[(((size_t)(b * 512 + d)) << 12) + t] = pk;
      }
    }
  }
}

__global__ __launch_bounds__(256, 2) void attn_score(
    const unsigned short* __restrict__ qb, const unsigned short* __restrict__ kb,
    unsigned short* __restrict__ P, const float* __restrict__ decay_logit) {
  __shared__ unsigned short As[2][8192];
  __shared__ unsigned short Bs[2][8192];
  const int tid = threadIdx.x;
  const int wave = tid >> 6, lane = tid & 63, quad = lane >> 4, l16 = lane & 15;
  const int wm = wave >> 1, wn = wave & 1;
  const int id = blockIdx.x;
  const int r8 = id & 7, j = id >> 3;
  const int mt0 = r8 * 16 + j / 3;
  const int sub = j % 3;
  const int m0 = mt0 * 128;
  const int b = mt0 >> 5;
  const int t0 = (mt0 & 31) * 128;
  const int s0 = t0 + sub * 128;
  const int xr = l16 & 7;

  const float dl = decay_logit[0];
  const float decay = 1.f / (1.f + __expf(-dl));
  const float l2d = __log2f(decay);

  float4v acc[4][4];
#pragma unroll
  for (int i = 0; i < 4; ++i)
#pragma unroll
    for (int jj = 0; jj < 4; ++jj) acc[i][jj] = (float4v)0.f;

  STAGE_SC(0, 0);
  __syncthreads();
  for (int t = 0; t < 8; ++t) {
    const int bi = t & 1;
    if (t < 7) STAGE_SC(bi ^ 1, (t + 1) * 64);
    GEMM_STEP(bi);
    __syncthreads();
  }

#pragma unroll
  for (int mtq = 0; mtq < 4; ++mtq) {
    const int mloc = wm * 64 + mtq * 16 + quad * 4;
#pragma unroll
    for (int nt = 0; nt < 4; ++nt) {
      const int scol = sub * 128 + wn * 64 + nt * 16 + l16;
      const int valid_s = (t0 + scol < T_SEQ) ? 1 : 0;
#pragma unroll
      for (int r = 0; r < 4; ++r) {
        const int dd = scol - (mloc + r);
        float w = 0.f;
        if (dd > 0 && valid_s) w = exp2f((float)(dd - 1) * l2d);
        P[(size_t)(m0 + mloc + r) * 384 + scol] = f2bf(acc[mtq][nt][r] * w);
      }
    }
  }
}

__global__ __launch_bounds__(256, 2) void attn_pv(
    const unsigned short* __restrict__ P, const unsigned short* __restrict__ vT,
    unsigned short* __restrict__ retr) {
  __shared__ unsigned short As[2][8192];
  __shared__ unsigned short Bs[2][8192];
  const int tid = threadIdx.x;
  const int wave = tid >> 6, lane = tid & 63, quad = lane >> 4, l16 = lane & 15;
  const int wm = wave >> 1, wn = wave & 1;
  const int id = blockIdx.x;
  const int r8 = id & 7, j = id >> 3;
  const int mt0 = r8 * 16 + j / 4;
  const int n0 = (j % 4) * 128;
  const int m0 = mt0 * 128;
  const int b = mt0 >> 5;
  const int t0 = (mt0 & 31) * 128;
  const int xr = l16 & 7;

  float4v acc[4][4];
#pragma unroll
  for (int i = 0; i < 4; ++i)
#pragma unroll
    for (int jj = 0; jj < 4; ++jj) acc[i][jj] = (float4v)0.f;

  STAGE_PV(0, 0);
  __syncthreads();
  for (int t = 0; t < 6; ++t) {
    const int bi = t & 1;
    if (t < 5) STAGE_PV(bi ^ 1, (t + 1) * 64);
    GEMM_STEP(bi);
    __syncthreads();
  }

  const int row0 = m0 + wm * 64;
#pragma unroll
  for (int mtq = 0; mtq < 4; ++mtq) {
    const int row = row0 + mtq * 16 + quad * 4;
#pragma unroll
    for (int nt = 0; nt < 4; ++nt) {
      const int col = n0 + wn * 64 + nt * 16 + l16;
#pragma unroll
      for (int r = 0; r < 4; ++r)
        retr[(size_t)(row + r) * 512 + col] = f2bf(acc[mtq][nt][r]);
    }
  }
}

__global__ __launch_bounds__(256, 2) void gemm_out(
    const unsigned short* __restrict__ A, const float* __restrict__ Wo,
    const float* __restrict__ osc, float* __restrict__ out) {
  __shared__ unsigned short As[2][8192];
  __shared__ unsigned short Bs[2][8192];
  const int tid = threadIdx.x;
  const int wave = tid >> 6, lane = tid & 63, quad = lane >> 4, l16 = lane & 15;
  const int wm = wave >> 1, wn = wave & 1;
  const int id = blockIdx.x;
  const int r8 = id & 7, j = id >> 3;
  const int m0 = (r8 * 16 + j / 4) * 128;
  const int n0 = (j % 4) * 128;
  const float scale = osc[0];
  const int xr = l16 & 7;

  float4v acc[4][4];
#pragma unroll
  for (int i = 0; i < 4; ++i)
#pragma unroll
    for (int jj = 0; jj < 4; ++jj) acc[i][jj] = (float4v)0.f;

  STAGE_OUT(0, 0);
  __syncthreads();
  for (int t = 0; t < 8; ++t) {
    const int bi = t & 1;
    if (t < 7) STAGE_OUT(bi ^ 1, (t + 1) * 64);
    GEMM_STEP(bi);
    __syncthreads();
  }

  const int row0 = m0 + wm * 64;
#pragma unroll
  for (int mt = 0; mt < 4; ++mt) {
    const int row = row0 + mt * 16 + quad * 4;
#pragma unroll
    for (int nt = 0; nt < 4; ++nt) {
      const int col = n0 + wn * 64 + nt * 16 + l16;
#pragma unroll
      for (int r = 0; r < 4; ++r)
        out[(size_t)(row + r) * 512 + col] = acc[mt][nt][r] * scale;
    }
  }
}

extern "C" void kernel_launch(void* const* d_in, const int* in_sizes, int n_in,
                              void* d_out, int out_size, void* d_ws, size_t ws_size,
                              hipStream_t stream) {
  const float* X  = (const float*)d_in[0];
  const float* Wq = (const float*)d_in[1];
  const float* Wk = (const float*)d_in[2];
  const float* Wv = (const float*)d_in[3];
  const float* Wo = (const float*)d_in[4];
  const float* dl = (const float*)d_in[5];
  const float* os = (const float*)d_in[6];
  float* out = (float*)d_out;

  // ws: qb 16MiB | kb 16MiB | vT 16MiB
  unsigned short* qb = (unsigned short*)d_ws;
  unsigned short* kb = qb + (size_t)16384 * 512;
  unsigned short* vT = kb + (size_t)16384 * 512;
  // d_out scratch: xbf 16MiB + wcat 1.5MiB; P (12.6MiB) overlays xbf.
  unsigned short* xbf  = (unsigned short*)d_out;
  unsigned short* wcat = xbf + (size_t)16384 * 512;
  unsigned short* P    = xbf;

  const float4v* X4  = (const float4v*)X;
  const float4v* Wq4 = (const float4v*)Wq;
  const float4v* Wk4 = (const float4v*)Wk;
  const float4v* Wv4 = (const float4v*)Wv;

  void* args[] = {(void*)&X4,  (void*)&Wq4, (void*)&Wk4, (void*)&Wv4,
                  (void*)&Wo,  (void*)&dl,  (void*)&os,  (void*)&qb,
                  (void*)&kb,  (void*)&vT,  (void*)&xbf, (void*)&wcat,
                  (void*)&P,   (void*)&out};
  hipError_t e = hipLaunchCooperativeKernel((void*)mega, dim3(512), dim3(256),
                                            args, 0, stream);
  if (e != hipSuccess) {
    // fallback: 5-kernel v7 path
    convert_pre<<<8960, 256, 0, stream>>>(X4, Wq4, Wk4, Wv4, (us4*)xbf,
                                          (us4*)wcat);
    gemm_qkv<<<1536, 256, 0, stream>>>(xbf, wcat, qb, kb, vT);
    attn_score<<<384, 256, 0, stream>>>(qb, kb, P, dl);
    attn_pv<<<512, 256, 0, stream>>>(P, vT, qb);
    gemm_out<<<512, 256, 0, stream>>>(qb, Wo, os, out);
  }
}

// Round 10
// 176.138 us; speedup vs baseline: 3.7384x; 3.7384x over previous
//
// CausalDecayMemory: convert -> bf16 MFMA GEMMs -> banded-GEMM decay attn -> out proj.
// v10 = v7 byte-identical resubmit (best measured: 176.8us).
// v9 post-mortem: cooperative grid.sync() measured ~120us/sync at 512 blocks
// (mega 571us = ~93us work + 4 syncs) -> launch boundaries (~10-19us) are
// CHEAPER than any in-kernel grid-wide sync. v8 post-mortem: fp32 reg-staged
// qkv doubled FETCH + VALU (compiler sank the staging loads). v7 is the
// empirical optimum: all 5 kernels < the harness's own 43us fill dispatches,
// each GEMM at ~28% MFMA peak = the documented 2-phase structural ceiling
// (counted-vmcnt null on this structure per m139; T2 done; T5 null on 2ph).
//  attn_score: P[128x384] = Q@K^T, decay w in epilogue, bf16 P in d_out.
//  attn_pv:    R = P@V (vT [d][t] IS the B-operand; K=384, edge-clamped).
// Both + gemm_qkv/gemm_out: 128x128 tile, dbuf LDS 64KB, 2-phase pipeline,
// 0-conflict swizzle, 2 blocks/CU, XCD-swizzled grid.
// Decay window 3x128 s-tiles; decay^255~4e-6 -> truncation << 4.2e-2 thr.
#include <hip/hip_runtime.h>

#define T_SEQ 4096

typedef __attribute__((ext_vector_type(8))) short short8;
typedef __attribute__((ext_vector_type(4))) float float4v;
typedef __attribute__((ext_vector_type(4))) unsigned short us4;

__device__ __forceinline__ unsigned short f2bf(float f) {
  union { float f; unsigned u; } x; x.f = f;
  return (unsigned short)((x.u + 0x7FFFu + ((x.u >> 16) & 1u)) >> 16);
}

__device__ __forceinline__ float4v mfma16(short8 a, short8 b, float4v c) {
  return __builtin_amdgcn_mfma_f32_16x16x32_bf16(a, b, c, 0, 0, 0);
}

// async global->LDS, 16B per lane; lds arg must be wave-uniform base
#define GLD16(g, l)                                                          \
  __builtin_amdgcn_global_load_lds(                                          \
      (const __attribute__((address_space(1))) void*)(g),                    \
      (__attribute__((address_space(3))) void*)(l), 16, 0, 0)

// ---------------------------------------------------------------------------
// Kernel 0: fp32 -> bf16 convert. X (2097152 f4-groups) then Wq|Wk|Wv.
// ---------------------------------------------------------------------------
__global__ __launch_bounds__(256) void convert_pre(
    const float4v* __restrict__ X, const float4v* __restrict__ Wq,
    const float4v* __restrict__ Wk, const float4v* __restrict__ Wv,
    us4* __restrict__ xbf, us4* __restrict__ wcat) {
  const int gid = blockIdx.x * 256 + threadIdx.x;
  const int XG = 2097152, WG = 65536;
  float4v v;
  us4* dst;
  if (gid < XG) {
    v = X[gid];
    dst = xbf + gid;
  } else {
    const int g2 = gid - XG;
    const float4v* W = (g2 < WG) ? Wq : (g2 < 2 * WG) ? Wk : Wv;
    v = W[g2 & (WG - 1)];
    dst = wcat + g2;
  }
  us4 p;
#pragma unroll
  for (int r = 0; r < 4; ++r) p[r] = f2bf(v[r]);
  *dst = p;
}

// ---------------------------------------------------------------------------
// Kernel 1: QKV GEMM. 128x128 tile, 256 thr = 2x2 waves of 64x64, BK=64.
// Double-buffered LDS (As/Bs 2x16KB each = 64KB), 2-phase pipeline.
// grid 1536 linear, XCD-swizzled: XCD r owns m-tiles r*16..r*16+15 x 12 by.
// ---------------------------------------------------------------------------
__global__ __launch_bounds__(256, 2) void gemm_qkv(
    const unsigned short* __restrict__ A, const unsigned short* __restrict__ Bw,
    unsigned short* __restrict__ qb, unsigned short* __restrict__ kb,
    unsigned short* __restrict__ vT) {
  __shared__ unsigned short As[2][8192];  // 128 rows x 64 shorts, x2 buf
  __shared__ unsigned short Bs[2][8192];
  const int tid = threadIdx.x;
  const int wave = tid >> 6, lane = tid & 63, quad = lane >> 4, l16 = lane & 15;
  const int wm = wave >> 1, wn = wave & 1;
  const int id = blockIdx.x;
  const int r8 = id & 7, j = id >> 3;
  const int m0 = (r8 * 16 + j / 12) * 128;
  const int by = j % 12;
  const int wid = by >> 2;
  const int n0 = (by & 3) * 128;
  const int nb0 = wid * 512 + n0;

  float4v acc[4][4];
#pragma unroll
  for (int i = 0; i < 4; ++i)
#pragma unroll
    for (int jj = 0; jj < 4; ++jj) acc[i][jj] = (float4v)0.f;

#define STAGE_QKV(bi, k0)                                                    \
  {                                                                          \
    _Pragma("unroll") for (int i = 0; i < 4; ++i) {                          \
      const int s = i * 256 + tid;                                           \
      const int row = s >> 3;                                                \
      const int kc = (s & 7) ^ (row & 7);                                    \
      GLD16(A + (size_t)(m0 + row) * 512 + (k0) + kc * 8,                    \
            &As[bi][(i * 256 + wave * 64) * 8]);                             \
    }                                                                        \
    _Pragma("unroll") for (int i = 0; i < 4; ++i) {                          \
      const int s = i * 256 + tid;                                           \
      const int row = s >> 3;                                                \
      const int kc = (s & 7) ^ (row & 7);                                    \
      GLD16(Bw + (size_t)(nb0 + row) * 512 + (k0) + kc * 8,                  \
            &Bs[bi][(i * 256 + wave * 64) * 8]);                             \
    }                                                                        \
  }

  const int xr = l16 & 7;

  STAGE_QKV(0, 0);
  __syncthreads();  // drains vmcnt -> buf0 visible
  for (int t = 0; t < 8; ++t) {
    const int bi = t & 1;
    if (t < 7) STAGE_QKV(bi ^ 1, (t + 1) * 64);  // in flight under compute
#pragma unroll
    for (int ks = 0; ks < 2; ++ks) {
      const int off = ((ks * 4 + quad) ^ xr) * 8;
      short8 af[4], bf[4];
#pragma unroll
      for (int mt = 0; mt < 4; ++mt)
        af[mt] = *(const short8*)&As[bi][(wm * 64 + mt * 16 + l16) * 64 + off];
#pragma unroll
      for (int nt = 0; nt < 4; ++nt)
        bf[nt] = *(const short8*)&Bs[bi][(wn * 64 + nt * 16 + l16) * 64 + off];
#pragma unroll
      for (int nt = 0; nt < 4; ++nt)
#pragma unroll
        for (int mt = 0; mt < 4; ++mt)
          acc[mt][nt] = mfma16(af[mt], bf[nt], acc[mt][nt]);
    }
    __syncthreads();  // next stage done + everyone finished reading buf bi
  }

  const int row0 = m0 + wm * 64;
  if (wid < 2) {
    unsigned short* outp = (wid == 0) ? qb : kb;
#pragma unroll
    for (int mt = 0; mt < 4; ++mt) {
      const int row = row0 + mt * 16 + quad * 4;
#pragma unroll
      for (int nt = 0; nt < 4; ++nt) {
        const int col = n0 + wn * 64 + nt * 16 + l16;
#pragma unroll
        for (int r = 0; r < 4; ++r)
          outp[(size_t)(row + r) * 512 + col] = f2bf(acc[mt][nt][r]);
      }
    }
  } else {
    // v transposed: C-layout r=0..3 = consecutive t at fixed d -> 8B store
#pragma unroll
    for (int mt = 0; mt < 4; ++mt) {
      const int row = row0 + mt * 16 + quad * 4;
      const int b = row >> 12, t = row & (T_SEQ - 1);
#pragma unroll
      for (int nt = 0; nt < 4; ++nt) {
        const int d = n0 + wn * 64 + nt * 16 + l16;
        us4 pk;
#pragma unroll
        for (int r = 0; r < 4; ++r) pk[r] = f2bf(acc[mt][nt][r]);
        *(us4*)&vT[(((size_t)(b * 512 + d)) << 12) + t] = pk;
      }
    }
  }
}

// ---------------------------------------------------------------------------
// Kernel 2a: attn_score. P[m-tile 128 x band 384] = Q @ K^T with decay
// weights in epilogue. grid 384: (m-tile mt, band-subtile sub of 128).
// Same 2-phase dbuf structure; K staging rows clamped (w=0 kills them).
// P bf16 [16384][384] row-major.
// ---------------------------------------------------------------------------
__global__ __launch_bounds__(256, 2) void attn_score(
    const unsigned short* __restrict__ qb, const unsigned short* __restrict__ kb,
    unsigned short* __restrict__ P, const float* __restrict__ decay_logit) {
  __shared__ unsigned short As[2][8192];
  __shared__ unsigned short Bs[2][8192];
  const int tid = threadIdx.x;
  const int wave = tid >> 6, lane = tid & 63, quad = lane >> 4, l16 = lane & 15;
  const int wm = wave >> 1, wn = wave & 1;
  const int id = blockIdx.x;
  const int r8 = id & 7, j = id >> 3;   // j 0..47
  const int mt = r8 * 16 + j / 3;       // m-tile 0..127
  const int sub = j % 3;
  const int m0 = mt * 128;              // global row base
  const int b = mt >> 5;
  const int t0 = (mt & 31) * 128;       // local t base of this m-tile
  const int s0 = t0 + sub * 128;        // local s base of this block's band

  const float dl = decay_logit[0];
  const float decay = 1.f / (1.f + __expf(-dl));
  const float l2d = __log2f(decay);

  float4v acc[4][4];
#pragma unroll
  for (int i = 0; i < 4; ++i)
#pragma unroll
    for (int jj = 0; jj < 4; ++jj) acc[i][jj] = (float4v)0.f;

#define STAGE_SC(bi, k0)                                                     \
  {                                                                          \
    _Pragma("unroll") for (int i = 0; i < 4; ++i) {                          \
      const int s = i * 256 + tid;                                           \
      const int row = s >> 3;                                                \
      const int kc = (s & 7) ^ (row & 7);                                    \
      GLD16(qb + (size_t)(m0 + row) * 512 + (k0) + kc * 8,                   \
            &As[bi][(i * 256 + wave * 64) * 8]);                             \
    }                                                                        \
    _Pragma("unroll") for (int i = 0; i < 4; ++i) {                          \
      const int s = i * 256 + tid;                                           \
      const int row = s >> 3;                                                \
      const int kc = (s & 7) ^ (row & 7);                                    \
      int sl = s0 + row;                                                     \
      if (sl > T_SEQ - 1) sl = T_SEQ - 1;                                    \
      GLD16(kb + ((size_t)(b * T_SEQ + sl)) * 512 + (k0) + kc * 8,           \
            &Bs[bi][(i * 256 + wave * 64) * 8]);                             \
    }                                                                        \
  }

  const int xr = l16 & 7;

  STAGE_SC(0, 0);
  __syncthreads();
  for (int t = 0; t < 8; ++t) {
    const int bi = t & 1;
    if (t < 7) STAGE_SC(bi ^ 1, (t + 1) * 64);
#pragma unroll
    for (int ks = 0; ks < 2; ++ks) {
      const int off = ((ks * 4 + quad) ^ xr) * 8;
      short8 af[4], bf[4];
#pragma unroll
      for (int mtq = 0; mtq < 4; ++mtq)
        af[mtq] = *(const short8*)&As[bi][(wm * 64 + mtq * 16 + l16) * 64 + off];
#pragma unroll
      for (int nt = 0; nt < 4; ++nt)
        bf[nt] = *(const short8*)&Bs[bi][(wn * 64 + nt * 16 + l16) * 64 + off];
#pragma unroll
      for (int nt = 0; nt < 4; ++nt)
#pragma unroll
        for (int mtq = 0; mtq < 4; ++mtq)
          acc[mtq][nt] = mfma16(af[mtq], bf[nt], acc[mtq][nt]);
    }
    __syncthreads();
  }

  // epilogue: w = decay^(dd-1) for dd>0 else 0; dd = scol - mlocal (tile-local)
#pragma unroll
  for (int mtq = 0; mtq < 4; ++mtq) {
    const int mloc = wm * 64 + mtq * 16 + quad * 4;
#pragma unroll
    for (int nt = 0; nt < 4; ++nt) {
      const int scol = sub * 128 + wn * 64 + nt * 16 + l16;
      const int valid_s = (t0 + scol < T_SEQ) ? 1 : 0;
#pragma unroll
      for (int r = 0; r < 4; ++r) {
        const int dd = scol - (mloc + r);
        float w = 0.f;
        if (dd > 0 && valid_s) w = exp2f((float)(dd - 1) * l2d);
        P[(size_t)(m0 + mloc + r) * 384 + scol] = f2bf(acc[mtq][nt][r] * w);
      }
    }
  }
}

// ---------------------------------------------------------------------------
// Kernel 2b: attn_pv. R[128x128] = P[128x384] @ V; B-operand is vT [d][t]
// directly (k-dim = t = t0+k). K=384 -> 6 k-steps. Band-edge t clamped to
// 4088 (clamped columns multiply P=0). grid 512: (m-panel, 4 n-subtiles).
// ---------------------------------------------------------------------------
__global__ __launch_bounds__(256, 2) void attn_pv(
    const unsigned short* __restrict__ P, const unsigned short* __restrict__ vT,
    unsigned short* __restrict__ retr) {
  __shared__ unsigned short As[2][8192];
  __shared__ unsigned short Bs[2][8192];
  const int tid = threadIdx.x;
  const int wave = tid >> 6, lane = tid & 63, quad = lane >> 4, l16 = lane & 15;
  const int wm = wave >> 1, wn = wave & 1;
  const int id = blockIdx.x;
  const int r8 = id & 7, j = id >> 3;   // j 0..63
  const int mt = r8 * 16 + j / 4;       // m-tile 0..127
  const int n0 = (j % 4) * 128;
  const int m0 = mt * 128;
  const int b = mt >> 5;
  const int t0 = (mt & 31) * 128;

  float4v acc[4][4];
#pragma unroll
  for (int i = 0; i < 4; ++i)
#pragma unroll
    for (int jj = 0; jj < 4; ++jj) acc[i][jj] = (float4v)0.f;

#define STAGE_PV(bi, k0)                                                     \
  {                                                                          \
    _Pragma("unroll") for (int i = 0; i < 4; ++i) {                          \
      const int s = i * 256 + tid;                                           \
      const int row = s >> 3;                                                \
      const int kc = (s & 7) ^ (row & 7);                                    \
      GLD16(P + (size_t)(m0 + row) * 384 + (k0) + kc * 8,                    \
            &As[bi][(i * 256 + wave * 64) * 8]);                             \
    }                                                                        \
    _Pragma("unroll") for (int i = 0; i < 4; ++i) {                          \
      const int s = i * 256 + tid;                                           \
      const int row = s >> 3;                                                \
      const int kc = (s & 7) ^ (row & 7);                                    \
      int tt = t0 + (k0) + kc * 8;                                           \
      if (tt > T_SEQ - 8) tt = T_SEQ - 8;                                    \
      GLD16(vT + (((size_t)(b * 512 + n0 + row)) << 12) + tt,                \
            &Bs[bi][(i * 256 + wave * 64) * 8]);                             \
    }                                                                        \
  }

  const int xr = l16 & 7;

  STAGE_PV(0, 0);
  __syncthreads();
  for (int t = 0; t < 6; ++t) {
    const int bi = t & 1;
    if (t < 5) STAGE_PV(bi ^ 1, (t + 1) * 64);
#pragma unroll
    for (int ks = 0; ks < 2; ++ks) {
      const int off = ((ks * 4 + quad) ^ xr) * 8;
      short8 af[4], bf[4];
#pragma unroll
      for (int mtq = 0; mtq < 4; ++mtq)
        af[mtq] = *(const short8*)&As[bi][(wm * 64 + mtq * 16 + l16) * 64 + off];
#pragma unroll
      for (int nt = 0; nt < 4; ++nt)
        bf[nt] = *(const short8*)&Bs[bi][(wn * 64 + nt * 16 + l16) * 64 + off];
#pragma unroll
      for (int nt = 0; nt < 4; ++nt)
#pragma unroll
        for (int mtq = 0; mtq < 4; ++mtq)
          acc[mtq][nt] = mfma16(af[mtq], bf[nt], acc[mtq][nt]);
    }
    __syncthreads();
  }

  const int row0 = m0 + wm * 64;
#pragma unroll
  for (int mtq = 0; mtq < 4; ++mtq) {
    const int row = row0 + mtq * 16 + quad * 4;
#pragma unroll
    for (int nt = 0; nt < 4; ++nt) {
      const int col = n0 + wn * 64 + nt * 16 + l16;
#pragma unroll
      for (int r = 0; r < 4; ++r)
        retr[(size_t)(row + r) * 512 + col] = f2bf(acc[mtq][nt][r]);
    }
  }
}

// ---------------------------------------------------------------------------
// Kernel 3: out = (retrieved @ Wo^T) * out_scale, fp32 out. Same 2-phase
// structure; A via GLD16, B (Wo fp32) converted in-reg during stage.
// grid 512 linear, XCD-swizzled (16 m-panels x 4 by per XCD).
// ---------------------------------------------------------------------------
__global__ __launch_bounds__(256, 2) void gemm_out(
    const unsigned short* __restrict__ A, const float* __restrict__ Wo,
    const float* __restrict__ osc, float* __restrict__ out) {
  __shared__ unsigned short As[2][8192];
  __shared__ unsigned short Bs[2][8192];
  const int tid = threadIdx.x;
  const int wave = tid >> 6, lane = tid & 63, quad = lane >> 4, l16 = lane & 15;
  const int wm = wave >> 1, wn = wave & 1;
  const int id = blockIdx.x;
  const int r8 = id & 7, j = id >> 3;
  const int m0 = (r8 * 16 + j / 4) * 128;
  const int n0 = (j % 4) * 128;
  const float scale = osc[0];

  float4v acc[4][4];
#pragma unroll
  for (int i = 0; i < 4; ++i)
#pragma unroll
    for (int jj = 0; jj < 4; ++jj) acc[i][jj] = (float4v)0.f;

#define STAGE_OUT(bi, k0)                                                    \
  {                                                                          \
    _Pragma("unroll") for (int i = 0; i < 4; ++i) {                          \
      const int s = i * 256 + tid;                                           \
      const int row = s >> 3;                                                \
      const int kc = (s & 7) ^ (row & 7);                                    \
      GLD16(A + (size_t)(m0 + row) * 512 + (k0) + kc * 8,                    \
            &As[bi][(i * 256 + wave * 64) * 8]);                             \
    }                                                                        \
    _Pragma("unroll") for (int i = 0; i < 4; ++i) {                          \
      const int s = i * 256 + tid;                                           \
      const int row = s >> 3;                                                \
      const int kc = (s & 7) ^ (row & 7);                                    \
      const float* gw = Wo + (size_t)(n0 + row) * 512 + (k0) + kc * 8;       \
      const float4v w0 = ((const float4v*)gw)[0];                            \
      const float4v w1 = ((const float4v*)gw)[1];                            \
      short8 pk;                                                             \
      _Pragma("unroll") for (int r = 0; r < 4; ++r) {                        \
        pk[r] = (short)f2bf(w0[r]);                                          \
        pk[4 + r] = (short)f2bf(w1[r]);                                      \
      }                                                                      \
      *(short8*)&Bs[bi][s * 8] = pk;                                         \
    }                                                                        \
  }

  const int xr = l16 & 7;

  STAGE_OUT(0, 0);
  __syncthreads();
  for (int t = 0; t < 8; ++t) {
    const int bi = t & 1;
    if (t < 7) STAGE_OUT(bi ^ 1, (t + 1) * 64);
#pragma unroll
    for (int ks = 0; ks < 2; ++ks) {
      const int off = ((ks * 4 + quad) ^ xr) * 8;
      short8 af[4], bf[4];
#pragma unroll
      for (int mt = 0; mt < 4; ++mt)
        af[mt] = *(const short8*)&As[bi][(wm * 64 + mt * 16 + l16) * 64 + off];
#pragma unroll
      for (int nt = 0; nt < 4; ++nt)
        bf[nt] = *(const short8*)&Bs[bi][(wn * 64 + nt * 16 + l16) * 64 + off];
#pragma unroll
      for (int nt = 0; nt < 4; ++nt)
#pragma unroll
        for (int mt = 0; mt < 4; ++mt)
          acc[mt][nt] = mfma16(af[mt], bf[nt], acc[mt][nt]);
    }
    __syncthreads();
  }

  const int row0 = m0 + wm * 64;
#pragma unroll
  for (int mt = 0; mt < 4; ++mt) {
    const int row = row0 + mt * 16 + quad * 4;
#pragma unroll
    for (int nt = 0; nt < 4; ++nt) {
      const int col = n0 + wn * 64 + nt * 16 + l16;
#pragma unroll
      for (int r = 0; r < 4; ++r)
        out[(size_t)(row + r) * 512 + col] = acc[mt][nt][r] * scale;
    }
  }
}

extern "C" void kernel_launch(void* const* d_in, const int* in_sizes, int n_in,
                              void* d_out, int out_size, void* d_ws, size_t ws_size,
                              hipStream_t stream) {
  const float* X  = (const float*)d_in[0];
  const float* Wq = (const float*)d_in[1];
  const float* Wk = (const float*)d_in[2];
  const float* Wv = (const float*)d_in[3];
  const float* Wo = (const float*)d_in[4];
  const float* dl = (const float*)d_in[5];
  const float* os = (const float*)d_in[6];
  float* out = (float*)d_out;

  // ws: qb 16MiB | kb 16MiB | vT 16MiB
  unsigned short* qb = (unsigned short*)d_ws;
  unsigned short* kb = qb + (size_t)16384 * 512;
  unsigned short* vT = kb + (size_t)16384 * 512;
  // d_out scratch: xbf (16MiB) + Wcat (1.5MiB), dead after gemm_qkv;
  // P (12.6MiB) reuses the xbf region, dead before gemm_out writes out.
  unsigned short* xbf  = (unsigned short*)d_out;
  unsigned short* wcat = xbf + (size_t)16384 * 512;
  unsigned short* P    = xbf;

  convert_pre<<<8960, 256, 0, stream>>>((const float4v*)X, (const float4v*)Wq,
                                        (const float4v*)Wk, (const float4v*)Wv,
                                        (us4*)xbf, (us4*)wcat);
  gemm_qkv<<<1536, 256, 0, stream>>>(xbf, wcat, qb, kb, vT);
  attn_score<<<384, 256, 0, stream>>>(qb, kb, P, dl);
  attn_pv<<<512, 256, 0, stream>>>(P, vT, qb);
  gemm_out<<<512, 256, 0, stream>>>(qb, Wo, os, out);
}